// Round 1
// baseline (51.019 us; speedup 1.0000x reference)
//
#include <hip/hip_runtime.h>

// WeightedBoxPool: out[b,j] = sum_t mask_weight[b,t,j] * [j == argmax_i (iou[i,j]>=thr[t])*score[i]]
// Equivalent: j "wins" threshold t iff no i with iou(i,j)>=thr[t] beats it,
// where beat = score[i]>score[j] || (score[i]==score[j] && i<j)  (argmax first-index tie-break).

constexpr int ILEN = 128;   // boxes per i-chunk staged in LDS
constexpr int JBLK = 256;   // threads per block, one j per thread
constexpr int TMAX = 8;     // max thresholds supported

__global__ __launch_bounds__(JBLK)
void wbp_loss_kernel(const float* __restrict__ box,     // [B,4,N]
                     const float* __restrict__ score,   // [B,1,N]
                     const float* __restrict__ thr,     // [T]
                     unsigned int* __restrict__ loss,   // [B*N] loss bitmasks (pre-zeroed)
                     int N, int T)
{
    const int jc  = blockIdx.x;
    const int b   = blockIdx.y;
    const int ic  = blockIdx.z;
    const int tid = threadIdx.x;
    const int j   = jc * JBLK + tid;
    const int i0  = ic * ILEN;
    const int cnt = min(ILEN, N - i0);

    // per-i record: x1,y1,x2,y2,score,area,(pad,pad) -> 32B, b128+b64 broadcast reads
    __shared__ float sh[ILEN][8];

    const float* bx1 = box + (size_t)(b * 4 + 0) * N;
    const float* by1 = box + (size_t)(b * 4 + 1) * N;
    const float* bx2 = box + (size_t)(b * 4 + 2) * N;
    const float* by2 = box + (size_t)(b * 4 + 3) * N;
    const float* sc  = score + (size_t)b * N;

    for (int k = tid; k < cnt; k += JBLK) {
        const int i = i0 + k;
        const float x1 = bx1[i], y1 = by1[i], x2 = bx2[i], y2 = by2[i];
        sh[k][0] = x1; sh[k][1] = y1; sh[k][2] = x2; sh[k][3] = y2;
        sh[k][4] = sc[i];
        sh[k][5] = (x2 - x1) * (y2 - y1);   // same expression as reference area
    }
    __syncthreads();

    float tr[TMAX];
    #pragma unroll
    for (int t = 0; t < TMAX; ++t) tr[t] = (t < T) ? thr[t] : 3.0e38f;

    float jx1 = 0.f, jy1 = 0.f, jx2 = 0.f, jy2 = 0.f, jarea = 0.f, js = 0.f;
    if (j < N) {
        jx1 = bx1[j]; jy1 = by1[j]; jx2 = bx2[j]; jy2 = by2[j];
        js  = sc[j];
        jarea = (jx2 - jx1) * (jy2 - jy1);
    }

    unsigned int bits = 0;
    const int kcnt = (j < N) ? cnt : 0;
    for (int k = 0; k < kcnt; ++k) {
        const float4 bxy = *(const float4*)&sh[k][0];   // x1,y1,x2,y2
        const float2 sa  = *(const float2*)&sh[k][4];   // score, area
        const int ig = i0 + k;
        const bool beat = (sa.x > js) || ((sa.x == js) && (ig < j));
        const float ltx = fmaxf(jx1, bxy.x);
        const float lty = fmaxf(jy1, bxy.y);
        const float rbx = fminf(jx2, bxy.z);
        const float rby = fminf(jy2, bxy.w);
        const float w = fmaxf(rbx - ltx, 0.0f);
        const float h = fmaxf(rby - lty, 0.0f);
        const float inter = w * h;
        if (beat && inter > 0.0f) {
            const float uni = (jarea + sa.y) - inter;   // (area_i + area_j) - inter, ref order
            const float iou = inter / uni;              // IEEE f32 division, matches numpy
            unsigned int m = 0;
            #pragma unroll
            for (int t = 0; t < TMAX; ++t)
                if (iou >= tr[t]) m |= (1u << t);
            bits |= m;
        }
    }

    if (j < N && bits) atomicOr(&loss[(size_t)b * N + j], bits);
}

__global__ __launch_bounds__(256)
void wbp_finalize_kernel(const float* __restrict__ mw,      // [B,T,N]
                         const unsigned int* __restrict__ loss,  // [B*N]
                         float* __restrict__ out,           // [B*N]
                         int N, int T, int BN)
{
    const int idx = blockIdx.x * blockDim.x + threadIdx.x;
    if (idx >= BN) return;
    const int b = idx / N;
    const int j = idx - b * N;
    const unsigned int w = loss[idx];
    float acc = 0.0f;
    for (int t = 0; t < T; ++t)
        if (!((w >> t) & 1u))
            acc += mw[(size_t)(b * T + t) * N + j];
    out[idx] = acc;
}

extern "C" void kernel_launch(void* const* d_in, const int* in_sizes, int n_in,
                              void* d_out, int out_size, void* d_ws, size_t ws_size,
                              hipStream_t stream)
{
    const float* mw  = (const float*)d_in[0];   // mask_weight [B,T,N]
    const float* box = (const float*)d_in[1];   // box         [B,4,N]
    const float* sc  = (const float*)d_in[2];   // score       [B,1,N]
    const float* thr = (const float*)d_in[3];   // thresholds  [T]
    float* out = (float*)d_out;                 // [B,1,N]

    const int BN = in_sizes[2];     // B*N
    const int T  = in_sizes[3];
    const int B  = 4;               // fixed by problem
    const int N  = BN / B;

    unsigned int* loss = (unsigned int*)d_ws;
    hipMemsetAsync(loss, 0, (size_t)BN * sizeof(unsigned int), stream);

    const int JC = (N + JBLK - 1) / JBLK;
    const int IC = (N + ILEN - 1) / ILEN;
    dim3 grid(JC, B, IC);
    wbp_loss_kernel<<<grid, JBLK, 0, stream>>>(box, sc, thr, loss, N, T);

    const int threads = 256;
    const int blocks = (BN + threads - 1) / threads;
    wbp_finalize_kernel<<<blocks, threads, 0, stream>>>(mw, loss, out, N, T, BN);
}

// Round 2
// 31.999 us; speedup vs baseline: 1.5944x; 1.5944x over previous
//
#include <hip/hip_runtime.h>

// WeightedBoxPool via running-max reformulation:
//   j loses threshold t  <=>  max_{i beats j} fl(iou(i,j)) >= t
// where beat = score[i]>score[j] || (score[i]==score[j] && i<j).
// Running max kept division-free as (n_best, d_best) with cross-multiply
// compare; ONE IEEE f32 divide per (j, i-chunk), atomicMax across chunks
// (float>=0 so uint-compare == float-compare). Final compare fl(n/d) >= t
// is bit-identical to the reference's per-i quotient comparisons.

constexpr int ILEN = 64;    // i-boxes per chunk (grid.z)
constexpr int JBLK = 256;   // threads per block, one j per thread

// Build 32B records [x1,y1,x2,y2,score,area,0,0] and zero maxq.
__global__ __launch_bounds__(256)
void wbp_prep(const float* __restrict__ box, const float* __restrict__ score,
              float4* __restrict__ rec, unsigned int* __restrict__ maxq,
              int N, int BN)
{
    const int idx = blockIdx.x * blockDim.x + threadIdx.x;
    if (idx >= BN) return;
    const int b = idx / N, i = idx - b * N;
    const float* bx = box + (size_t)b * 4 * N;
    const float x1 = bx[i], y1 = bx[N + i], x2 = bx[2 * N + i], y2 = bx[3 * N + i];
    const float s = score[idx];
    rec[(size_t)idx * 2 + 0] = make_float4(x1, y1, x2, y2);
    rec[(size_t)idx * 2 + 1] = make_float4(s, (x2 - x1) * (y2 - y1), 0.f, 0.f);
    maxq[idx] = 0u;
}

__global__ __launch_bounds__(JBLK)
void wbp_loss(const float* __restrict__ rec, unsigned int* __restrict__ maxq, int N)
{
    const int b   = blockIdx.y;
    const int j   = blockIdx.x * JBLK + (int)threadIdx.x;
    const int i0  = blockIdx.z * ILEN;
    const int cnt = min(ILEN, N - i0);
    const bool active = j < N;

    float jx1 = 0.f, jy1 = 0.f, jx2 = 0.f, jy2 = 0.f, js = 0.f, ja = 0.f;
    if (active) {
        const float* r = rec + ((size_t)b * N + j) * 8;
        jx1 = r[0]; jy1 = r[1]; jx2 = r[2]; jy2 = r[3]; js = r[4]; ja = r[5];
    }
    // Block-uniform i-stream -> scalar loads (s_load), off the VALU.
    const float* __restrict__ ri = rec + ((size_t)b * N + i0) * 8;

    float nb = 0.f, db = 1.f;   // running max quotient nb/db over beating i

    auto body = [&](int k) {
        const float ix1 = ri[k * 8 + 0];
        const float iy1 = ri[k * 8 + 1];
        const float ix2 = ri[k * 8 + 2];
        const float iy2 = ri[k * 8 + 3];
        const float is  = ri[k * 8 + 4];
        const float ia  = ri[k * 8 + 5];
        const int   ig  = i0 + k;

        const float ltx = fmaxf(jx1, ix1);
        const float lty = fmaxf(jy1, iy1);
        const float rbx = fminf(jx2, ix2);
        const float rby = fminf(jy2, iy2);
        const float w   = fmaxf(rbx - ltx, 0.f);
        const float h   = fmaxf(rby - lty, 0.f);
        const float inter = w * h;
        const float uni   = (ja + ia) - inter;     // fl(area_j+area_i) == fl(area_i+area_j)

        const bool beat   = (is > js) || ((is == js) && (ig < j));
        const bool better = (inter * db) > (nb * uni);  // inter/uni > nb/db (cross-mult)
        if (beat && better) { nb = inter; db = uni; }   // -> 2 cndmask, branchless
    };

    if (cnt == ILEN) {
        #pragma unroll 8
        for (int k = 0; k < ILEN; ++k) body(k);
    } else {
        for (int k = 0; k < cnt; ++k) body(k);
    }

    if (active && nb > 0.f) {
        const float q = nb / db;                   // IEEE f32 divide, once per chunk
        atomicMax(&maxq[(size_t)b * N + j], __float_as_uint(q));
    }
}

__global__ __launch_bounds__(256)
void wbp_fin(const float* __restrict__ mw, const float* __restrict__ thr,
             const unsigned int* __restrict__ maxq, float* __restrict__ out,
             int N, int T, int BN)
{
    const int idx = blockIdx.x * blockDim.x + threadIdx.x;
    if (idx >= BN) return;
    const int b = idx / N, jj = idx - b * N;
    const float q = __uint_as_float(maxq[idx]);
    float acc = 0.f;
    for (int t = 0; t < T; ++t)
        if (q < thr[t])                            // not lost at t
            acc += mw[(size_t)(b * T + t) * N + jj];
    out[idx] = acc;
}

extern "C" void kernel_launch(void* const* d_in, const int* in_sizes, int n_in,
                              void* d_out, int out_size, void* d_ws, size_t ws_size,
                              hipStream_t stream)
{
    const float* mw  = (const float*)d_in[0];   // [B,T,N]
    const float* box = (const float*)d_in[1];   // [B,4,N]
    const float* sc  = (const float*)d_in[2];   // [B,1,N]
    const float* thr = (const float*)d_in[3];   // [T]
    float* out = (float*)d_out;                 // [B,1,N]

    const int BN = in_sizes[2];
    const int T  = in_sizes[3];
    const int B  = 4;
    const int N  = BN / B;

    float*        rec  = (float*)d_ws;                              // BN*32 bytes
    unsigned int* maxq = (unsigned int*)((char*)d_ws + (size_t)BN * 32); // BN*4 bytes

    {
        const int thr_n = 256, blk = (BN + thr_n - 1) / thr_n;
        wbp_prep<<<blk, thr_n, 0, stream>>>(box, sc, (float4*)rec, maxq, N, BN);
    }
    {
        const int JC = (N + JBLK - 1) / JBLK;
        const int IC = (N + ILEN - 1) / ILEN;
        dim3 grid(JC, B, IC);
        wbp_loss<<<grid, JBLK, 0, stream>>>(rec, maxq, N);
    }
    {
        const int thr_n = 256, blk = (BN + thr_n - 1) / thr_n;
        wbp_fin<<<blk, thr_n, 0, stream>>>(mw, thr, maxq, out, N, T, BN);
    }
}